// Round 19
// baseline (2017.978 us; speedup 1.0000x reference)
//
#include <hip/hip_runtime.h>
#include <math.h>

typedef unsigned short u16;
typedef __bf16 bfx8 __attribute__((ext_vector_type(8)));
typedef float f32x4 __attribute__((ext_vector_type(4)));

#define NLAYER  8
#define NHEAD   16
#define DMODEL  1024
#define DHEAD   64
#define DFF     4096
#define NB      2
#define SEQ     1024
#define NVOCAB  32000
#define NTOK    (NB*SEQ)
#define EPSLN   1e-5f
#define VCHUNK  6400   // lm_head fallback chunking (ws-gated)
#define NSPLIT  2      // attention split-K factor (round-6/8 verified)

__device__ __forceinline__ float bf2f(u16 u) {
  union { unsigned int i; float f; } x; x.i = ((unsigned int)u) << 16; return x.f;
}
__device__ __forceinline__ u16 f2bf(float f) {
  unsigned int x = __float_as_uint(f);
  x += 0x7fffu + ((x >> 16) & 1u);          // RNE
  return (u16)(x >> 16);
}

#if defined(__has_builtin)
#if __has_builtin(__builtin_amdgcn_global_load_lds)
#define HAVE_GLL 1
#endif
#endif

// Async global->LDS: 64 lanes x 16B. lds_base is wave-uniform; HW adds lane*16.
__device__ __forceinline__ void gll16(const void* g, void* lds_base, int lane) {
#ifdef HAVE_GLL
  __builtin_amdgcn_global_load_lds((const __attribute__((address_space(1))) unsigned int*)g,
                                   (__attribute__((address_space(3))) unsigned int*)lds_base,
                                   16, 0, 0);
  (void)lane;
#else
  *(uint4*)((char*)lds_base + lane * 16) = *(const uint4*)g;
#endif
}

enum { EPI_QKV = 0, EPI_GELU_BIAS = 1, EPI_RESID = 2, EPI_RESID_BIAS = 3, EPI_LOGITS = 4 };

// ------------------------------------------------------------------
// 2-phase dbuf GEMM, BK=32 (r13-verified structure, zero bank conflicts).
// Tile census (r17/r18): lm_head 128x128 (4000 blk, 5/CU) | QKV 64x128 |
// FF1 64x128 | wo,FF2 64x64 (2/CU). Block-level TLP is the only lever that
// ever paid (r3/r12/r17); pipelining closed (r8/r10/r14 all lost).
// Swizzle key (row>>1)&3 on 64B rows, both-sides involution.
// ------------------------------------------------------------------
template <int EPI, int BM, int BN>
__global__ __launch_bounds__(256) void gemm_bt(
    const u16* __restrict__ A, const u16* __restrict__ Bt,
    const float* __restrict__ bias, u16* __restrict__ outb,
    float* __restrict__ outf, int M, int N, int K, int ldc)
{
  constexpr int ARND = BM / 64;
  constexpr int BRND = BN / 64;
  constexpr int MF = BM / 32;
  constexpr int NF = BN / 32;
  constexpr int ABYTES = BM * 32 * 2;
  constexpr int BBYTES = BN * 32 * 2;
  __shared__ __align__(16) u16 sA[2][BM * 32];
  __shared__ __align__(16) u16 sB[2][BN * 32];

  const int tid  = threadIdx.x;
  const int w    = tid >> 6;
  const int lane = tid & 63;
  const int l16  = lane & 15;
  const int hi   = lane >> 4;
  const int wm   = w >> 1;
  const int wn   = w & 1;

  const int nwg = gridDim.x;
  const int MB  = M / BM;
  const int orig = blockIdx.x;
  const int xcd = orig & 7, li = orig >> 3;
  const int q = nwg >> 3, r = nwg & 7;
  const int work = (xcd < r ? xcd * (q + 1) : r * (q + 1) + (xcd - r) * q) + li;
  const int m0 = (work % MB) * BM;
  const int n0 = (work / MB) * BN;

  const int srow = lane >> 2;
  const int su   = lane & 3;

  const u16* gA[ARND]; const u16* gB[BRND];
  int laOff[ARND]; int lbOff[BRND];
#pragma unroll
  for (int r2 = 0; r2 < ARND; r2++) {
    const int row = r2 * 64 + w * 16 + srow;
    const int gu = su ^ ((row >> 1) & 3);
    gA[r2] = A + (size_t)(m0 + row) * K + gu * 8;
    laOff[r2] = (r2 * 64 + w * 16) * 64;
  }
#pragma unroll
  for (int r2 = 0; r2 < BRND; r2++) {
    const int row = r2 * 64 + w * 16 + srow;
    const int gu = su ^ ((row >> 1) & 3);
    gB[r2] = Bt + (size_t)(n0 + row) * K + gu * 8;
    lbOff[r2] = (r2 * 64 + w * 16) * 64;
  }

  f32x4 acc[MF][NF];
#pragma unroll
  for (int i = 0; i < MF; i++)
#pragma unroll
    for (int j = 0; j < NF; j++)
#pragma unroll
      for (int r2 = 0; r2 < 4; r2++) acc[i][j][r2] = 0.0f;

#pragma unroll
  for (int r2 = 0; r2 < ARND; r2++) { gll16(gA[r2], (char*)sA[0] + laOff[r2], lane); gA[r2] += 32; }
#pragma unroll
  for (int r2 = 0; r2 < BRND; r2++) { gll16(gB[r2], (char*)sB[0] + lbOff[r2], lane); gB[r2] += 32; }
  __syncthreads();

  const int NT = K >> 5;
  int cur = 0;
  for (int t = 0; t < NT; ++t) {
    if (t + 1 < NT) {
      char* nA = (char*)sA[0] + (cur ^ 1) * ABYTES;
      char* nB = (char*)sB[0] + (cur ^ 1) * BBYTES;
#pragma unroll
      for (int r2 = 0; r2 < ARND; r2++) { gll16(gA[r2], nA + laOff[r2], lane); gA[r2] += 32; }
#pragma unroll
      for (int r2 = 0; r2 < BRND; r2++) { gll16(gB[r2], nB + lbOff[r2], lane); gB[r2] += 32; }
    }

    const char* cA = (const char*)sA[0] + cur * ABYTES;
    const char* cB = (const char*)sB[0] + cur * BBYTES;
    bfx8 aF[MF], bF[NF];
#pragma unroll
    for (int i = 0; i < MF; i++) {
      const int row = wm * (BM / 2) + i * 16 + l16;
      aF[i] = *(const bfx8*)(cA + row * 64 + ((hi ^ ((row >> 1) & 3)) << 4));
    }
#pragma unroll
    for (int j = 0; j < NF; j++) {
      const int row = wn * (BN / 2) + j * 16 + l16;
      bF[j] = *(const bfx8*)(cB + row * 64 + ((hi ^ ((row >> 1) & 3)) << 4));
    }
#pragma unroll
    for (int i = 0; i < MF; i++)
#pragma unroll
      for (int j = 0; j < NF; j++)
        acc[i][j] = __builtin_amdgcn_mfma_f32_16x16x32_bf16(aF[i], bF[j], acc[i][j], 0, 0, 0);
    __syncthreads();
    cur ^= 1;
  }

  const int rbase = m0 + wm * (BM / 2);
  const int cbase = n0 + wn * (BN / 2);
#pragma unroll
  for (int i = 0; i < MF; i++) {
#pragma unroll
    for (int j = 0; j < NF; j++) {
      const int gcol = cbase + j * 16 + l16;
      float bv = 0.0f;
      if constexpr (EPI == EPI_GELU_BIAS || EPI == EPI_RESID_BIAS) bv = bias[gcol];
#pragma unroll
      for (int r2 = 0; r2 < 4; r2++) {
        const int grow = rbase + i * 16 + hi * 4 + r2;
        float v = acc[i][j][r2];
        const size_t oi = (size_t)grow * ldc + gcol;
        if constexpr (EPI == EPI_QKV) {
          outb[oi] = f2bf(v);
        } else if constexpr (EPI == EPI_GELU_BIAS) {
          v += bv;
          v = 0.5f * v * (1.0f + erff(v * 0.70710678118654752f));
          outb[oi] = f2bf(v);
        } else if constexpr (EPI == EPI_RESID) {
          outf[oi] += v;
        } else if constexpr (EPI == EPI_RESID_BIAS) {
          outf[oi] += v + bv;
        } else {
          outf[oi] = v;
        }
      }
    }
  }
}

// LayerNorm, single-pass (sum + sumsq through one shuffle tree).
__global__ __launch_bounds__(256) void ln_kernel(
    const float* __restrict__ x, const float* __restrict__ w,
    const float* __restrict__ b, u16* __restrict__ out)
{
  const int row = blockIdx.x;
  const int tid = threadIdx.x;
  const float* xr = x + (size_t)row * DMODEL;
  float4 v = *(const float4*)(xr + tid * 4);
  __shared__ float sbuf[4], qbuf[4];
  float s = v.x + v.y + v.z + v.w;
  float ss = v.x * v.x + v.y * v.y + v.z * v.z + v.w * v.w;
#pragma unroll
  for (int o = 32; o > 0; o >>= 1) { s += __shfl_xor(s, o, 64); ss += __shfl_xor(ss, o, 64); }
  if ((tid & 63) == 0) { sbuf[tid >> 6] = s; qbuf[tid >> 6] = ss; }
  __syncthreads();
  const float mean = (sbuf[0] + sbuf[1] + sbuf[2] + sbuf[3]) * (1.0f / DMODEL);
  const float ex2  = (qbuf[0] + qbuf[1] + qbuf[2] + qbuf[3]) * (1.0f / DMODEL);
  const float rstd = rsqrtf(ex2 - mean * mean + EPSLN);
  const int c = tid * 4;
  float dv[4] = {v.x - mean, v.y - mean, v.z - mean, v.w - mean};
#pragma unroll
  for (int e = 0; e < 4; e++)
    out[(size_t)row * DMODEL + c + e] = f2bf(dv[e] * rstd * w[c + e] + b[c + e]);
}

// x = tok_emb[idx] + sinusoidal PE, fp32 in -> fp32 out.
__global__ __launch_bounds__(256) void embed_kernel(
    const int* __restrict__ idx, const float* __restrict__ tok, float* __restrict__ x)
{
  const int row = blockIdx.x;
  const int l = row & (SEQ - 1);
  const int t = idx[row];
  const int d = threadIdx.x * 4;
#pragma unroll
  for (int e = 0; e < 4; e++) {
    const int dd = d + e;
    const float freq = expf((float)(dd & ~1) * (-9.210340371976184f / (float)DMODEL));
    const float ang = (float)l * freq;
    const float pe = (dd & 1) ? cosf(ang) : sinf(ang);
    x[(size_t)row * DMODEL + dd] = tok[(size_t)t * DMODEL + dd] + pe;
  }
}

// 64x64-tile transpose body: fp32 in -> bf16 out, float4 loads, packed
// ushort2 stores. tile[64][65] breaks bank conflicts.
__device__ __forceinline__ void transpose64_body(
    const float* __restrict__ in, u16* __restrict__ out,
    int rows, int cols, int c0, int r0)
{
  __shared__ float tile[64][65];
  const int lx = threadIdx.x & 15, ly = threadIdx.x >> 4;
#pragma unroll
  for (int ii = 0; ii < 4; ii++) {
    const int rr = ly + ii * 16;
    const float4 v = *(const float4*)&in[(size_t)(r0 + rr) * cols + c0 + lx * 4];
    tile[rr][lx * 4 + 0] = v.x;
    tile[rr][lx * 4 + 1] = v.y;
    tile[rr][lx * 4 + 2] = v.z;
    tile[rr][lx * 4 + 3] = v.w;
  }
  __syncthreads();
  const int sx = threadIdx.x & 31, sy = threadIdx.x >> 5;
#pragma unroll
  for (int ii = 0; ii < 8; ii++) {
    const int cc = sy + ii * 8;
    const unsigned int a = f2bf(tile[sx * 2][cc]);
    const unsigned int b = f2bf(tile[sx * 2 + 1][cc]);
    *(unsigned int*)&out[(size_t)(c0 + cc) * rows + r0 + sx * 2] = a | (b << 16);
  }
}

// Generic 64x64 transpose: out[c][r] = (bf16)in[r][c].
__global__ __launch_bounds__(256) void transpose64_b(
    const float* __restrict__ in, u16* __restrict__ out, int rows, int cols)
{
  transpose64_body(in, out, rows, cols, blockIdx.x * 64, blockIdx.y * 64);
}

// Per-layer weight transpose, 64x64 tiles, layer batched on blockIdx.y.
__global__ __launch_bounds__(256) void transpose6_kernel(
    const float* __restrict__ wq, const float* __restrict__ wk,
    const float* __restrict__ wv, const float* __restrict__ wo,
    const float* __restrict__ w1, const float* __restrict__ w2,
    u16* __restrict__ wT, size_t outLayerStride)
{
  const size_t dd = (size_t)DMODEL * DMODEL, dff = (size_t)DMODEL * DFF;
  const int z = blockIdx.y;
  const int t = blockIdx.x;
  const float* in; u16* out; int rows, cols, cx, cy;
  u16* wTl = wT + (size_t)z * outLayerStride;
  if (t < 1024) {
    const int mat = t >> 8, tl = t & 255;
    const float* base = (mat == 0) ? wq : (mat == 1) ? wk : (mat == 2) ? wv : wo;
    in = base + (size_t)z * dd;
    out = wTl + (size_t)mat * dd; rows = DMODEL; cols = DMODEL;
    cx = tl & 15; cy = tl >> 4;
  } else if (t < 2048) {
    const int tl = t - 1024;
    in = w1 + (size_t)z * dff; out = wTl + 4 * dd; rows = DMODEL; cols = DFF;
    cx = tl & 63; cy = tl >> 6;
  } else {
    const int tl = t - 2048;
    in = w2 + (size_t)z * dff; out = wTl + 4 * dd + dff; rows = DFF; cols = DMODEL;
    cx = tl & 15; cy = tl >> 4;
  }
  transpose64_body(in, out, rows, cols, cx * 64, cy * 64);
}

// vt[(b*NH+h)*DHEAD + d][l] = qkv[b*SEQ+l][2*DMODEL + h*DHEAD + d]  (bf16)
__global__ __launch_bounds__(256) void vtrans_kernel(
    const u16* __restrict__ qkv, u16* __restrict__ vt)
{
  __shared__ u16 tile[32][33];
  const int bh = blockIdx.z;
  const int b = bh >> 4, hh = bh & 15;
  const int l0 = blockIdx.x * 32, d0 = blockIdx.y * 32;
  const int tx = threadIdx.x & 31, ty = threadIdx.x >> 5;
#pragma unroll
  for (int i = ty; i < 32; i += 8)
    tile[i][tx] = qkv[(size_t)(b * SEQ + l0 + i) * (3 * DMODEL) + 2 * DMODEL + hh * DHEAD + d0 + tx];
  __syncthreads();
#pragma unroll
  for (int i = ty; i < 32; i += 8)
    vt[(size_t)(bh * DHEAD + d0 + i) * SEQ + l0 + tx] = tile[tx][i];
}

// P-tile LDS: 32 rows x 128 cols bf16 (256B rows = 16x16B units).
__device__ __forceinline__ int plds_byte(int row, int col) {
  const int cu = col >> 3;
  const int scu = (cu & 8) | ((cu & 7) ^ (row & 7));
  return row * 256 + scu * 16 + (col & 7) * 2;
}

// Split-K flash attention partial, no max-tracking (r9 math), KVBLK=128,
// 1D grid + XCD chunk map. NEW (r19): opart stored as bf16 (halves the
// partial-O HBM round-trip; y is bf16 anyway so end-to-end error ~1 ulp).
__global__ __launch_bounds__(64) void attn_partial(
    const u16* __restrict__ qkv, const u16* __restrict__ vt,
    u16* __restrict__ opart, float* __restrict__ lpart)
{
  __shared__ __align__(16) u16 p_lds[32 * 128];
  const int lane = threadIdx.x;
  const int l16 = lane & 15, hi = lane >> 4;

  const int orig = blockIdx.x;
  const int work = (orig & 7) * (NSPLIT * NB * NHEAD * (SEQ / 32) / 8) + (orig >> 3);
  const int qt = work & 31;
  const int t1 = work >> 5;
  const int hh = t1 & 15;
  const int t2 = t1 >> 4;
  const int b  = t2 & 1;
  const int sp = t2 >> 1;

  const int q0 = qt * 32;
  const int T = (q0 + 159) >> 7;
  const int t_lo = (T * sp) >> 1;
  const int t_hi = (T * (sp + 1)) >> 1;

  const u16* qptr = qkv;
  const u16* kptr = qkv + DMODEL;
  const size_t rs3 = 3 * DMODEL;
  const size_t hoff = (size_t)hh * DHEAD;

  bfx8 aQ[2][2];
#pragma unroll
  for (int mt = 0; mt < 2; mt++)
#pragma unroll
    for (int kf = 0; kf < 2; kf++)
      aQ[mt][kf] = *(const bfx8*)&qptr[(size_t)(b * SEQ + q0 + mt * 16 + l16) * rs3 + hoff + kf * 32 + hi * 8];

  f32x4 o[2][4];
  float ssum[2][4];
#pragma unroll
  for (int mt = 0; mt < 2; mt++)
#pragma unroll
    for (int r = 0; r < 4; r++) ssum[mt][r] = 0.0f;
#pragma unroll
  for (int mt = 0; mt < 2; mt++)
#pragma unroll
    for (int dt = 0; dt < 4; dt++)
#pragma unroll
      for (int r = 0; r < 4; r++) o[mt][dt][r] = 0.0f;

  for (int kt = t_lo; kt < t_hi; kt++) {
    const int k0 = kt * 128;
    const bool diag = (kt == T - 1);

    float rs[2][4];
#pragma unroll
    for (int mt = 0; mt < 2; mt++)
#pragma unroll
      for (int r = 0; r < 4; r++) rs[mt][r] = 0.0f;

#pragma unroll
    for (int hf = 0; hf < 2; hf++) {
      const int kh0 = k0 + hf * 64;
      bfx8 bK[4][2];
#pragma unroll
      for (int nt = 0; nt < 4; nt++)
#pragma unroll
        for (int kf = 0; kf < 2; kf++)
          bK[nt][kf] = *(const bfx8*)&kptr[(size_t)(b * SEQ + kh0 + nt * 16 + l16) * rs3 + hoff + kf * 32 + hi * 8];

      f32x4 s[2][4];
#pragma unroll
      for (int mt = 0; mt < 2; mt++)
#pragma unroll
        for (int nt = 0; nt < 4; nt++) {
#pragma unroll
          for (int r = 0; r < 4; r++) s[mt][nt][r] = 0.0f;
          s[mt][nt] = __builtin_amdgcn_mfma_f32_16x16x32_bf16(aQ[mt][0], bK[nt][0], s[mt][nt], 0, 0, 0);
          s[mt][nt] = __builtin_amdgcn_mfma_f32_16x16x32_bf16(aQ[mt][1], bK[nt][1], s[mt][nt], 0, 0, 0);
        }

#pragma unroll
      for (int mt = 0; mt < 2; mt++) {
#pragma unroll
        for (int r = 0; r < 4; r++) {
          const int row_l = mt * 16 + hi * 4 + r;
          const int qrow = q0 + row_l;
#pragma unroll
          for (int nt = 0; nt < 4; nt++) {
            const float sv = s[mt][nt][r] * 0.125f;
            const bool mask = diag && (kh0 + nt * 16 + l16 > qrow);
            const float p = mask ? 0.0f : __expf(sv);
            rs[mt][r] += p;
            *(__bf16*)((char*)p_lds + plds_byte(row_l, hf * 64 + nt * 16 + l16)) = (__bf16)p;
          }
        }
      }
    }

#pragma unroll
    for (int mt = 0; mt < 2; mt++)
#pragma unroll
      for (int r = 0; r < 4; r++) {
        float rsum = rs[mt][r];
#pragma unroll
        for (int t = 1; t < 16; t <<= 1) rsum += __shfl_xor(rsum, t, 64);
        ssum[mt][r] += rsum;
      }
    __syncthreads();

    const size_t vbase = (size_t)(b * NHEAD + hh) * DHEAD * SEQ;
#pragma unroll
    for (int hf = 0; hf < 2; hf++) {
      bfx8 pa[2][2];
#pragma unroll
      for (int mt = 0; mt < 2; mt++) {
        const int row = mt * 16 + l16;
#pragma unroll
        for (int kf = 0; kf < 2; kf++) {
          const int u = hf * 8 + kf * 4 + hi;
          const int su_ = (u & 8) | ((u & 7) ^ (row & 7));
          pa[mt][kf] = *(const bfx8*)((const char*)p_lds + row * 256 + su_ * 16);
        }
      }
      bfx8 bV[4][2];
#pragma unroll
      for (int dt = 0; dt < 4; dt++)
#pragma unroll
        for (int kf = 0; kf < 2; kf++)
          bV[dt][kf] = *(const bfx8*)&vt[vbase + (size_t)(dt * 16 + l16) * SEQ + k0 + hf * 64 + kf * 32 + hi * 8];
#pragma unroll
      for (int mt = 0; mt < 2; mt++)
#pragma unroll
        for (int dt = 0; dt < 4; dt++) {
          o[mt][dt] = __builtin_amdgcn_mfma_f32_16x16x32_bf16(pa[mt][0], bV[dt][0], o[mt][dt], 0, 0, 0);
          o[mt][dt] = __builtin_amdgcn_mfma_f32_16x16x32_bf16(pa[mt][1], bV[dt][1], o[mt][dt], 0, 0, 0);
        }
    }
    __syncthreads();
  }

  const size_t pbase = (((size_t)sp * NB + b) * NHEAD + hh) * SEQ + q0;
#pragma unroll
  for (int mt = 0; mt < 2; mt++) {
#pragma unroll
    for (int r = 0; r < 4; r++) {
      const int row_l = mt * 16 + hi * 4 + r;
      const size_t rg = pbase + row_l;
      if (l16 == 0) lpart[rg] = ssum[mt][r];
#pragma unroll
      for (int dt = 0; dt < 4; dt++)
        opart[rg * DHEAD + dt * 16 + l16] = f2bf(o[mt][dt][r]);
    }
  }
}

// Combine NSPLIT partials (all weights 1, no max) -> y bf16.
__global__ __launch_bounds__(256) void attn_combine(
    const u16* __restrict__ opart, const float* __restrict__ lpart,
    u16* __restrict__ y)
{
  const int row = blockIdx.x;
  const int b = row >> 10;
  const int l = row & (SEQ - 1);
  const int t = threadIdx.x;
  const int hh = t >> 4;
  const int d0 = (t & 15) * 4;
  const size_t base = ((size_t)b * NHEAD + hh) * SEQ + l;
  const size_t stride = (size_t)NB * NHEAD * SEQ;
  float wsum = 0.0f;
  float4 acc = make_float4(0.f, 0.f, 0.f, 0.f);
#pragma unroll
  for (int i = 0; i < NSPLIT; i++) {
    wsum += lpart[base + i * stride];
    const ushort4 ov = *(const ushort4*)&opart[(base + i * stride) * DHEAD + d0];
    acc.x += bf2f(ov.x); acc.y += bf2f(ov.y);
    acc.z += bf2f(ov.z); acc.w += bf2f(ov.w);
  }
  const float dn = 1.0f / wsum;
  u16* yp = y + (size_t)row * DMODEL + hh * DHEAD + d0;
  yp[0] = f2bf(acc.x * dn);
  yp[1] = f2bf(acc.y * dn);
  yp[2] = f2bf(acc.z * dn);
  yp[3] = f2bf(acc.w * dn);
}

extern "C" void kernel_launch(void* const* d_in, const int* in_sizes, int n_in,
                              void* d_out, int out_size, void* d_ws, size_t ws_size,
                              hipStream_t stream)
{
  (void)in_sizes; (void)n_in; (void)out_size;
  const int*   idx  = (const int*)d_in[0];
  const float* tok  = (const float*)d_in[1];
  const float* ln1w = (const float*)d_in[2];
  const float* ln1b = (const float*)d_in[3];
  const float* wq   = (const float*)d_in[4];
  const float* wk   = (const float*)d_in[5];
  const float* wv   = (const float*)d_in[6];
  const float* wo   = (const float*)d_in[7];
  const float* ln2w = (const float*)d_in[8];
  const float* ln2b = (const float*)d_in[9];
  const float* w1   = (const float*)d_in[10];
  const float* b1   = (const float*)d_in[11];
  const float* w2   = (const float*)d_in[12];
  const float* b2   = (const float*)d_in[13];
  const float* lnfw = (const float*)d_in[14];
  const float* lnfb = (const float*)d_in[15];
  const float* lmh  = (const float*)d_in[16];
  float* out = (float*)d_out;

  char* ws = (char*)d_ws;
  size_t off = 0;
  auto alloc = [&](size_t bytes) -> void* {
    void* p = ws + off;
    off += (bytes + 255) & ~(size_t)255;
    return p;
  };
  float* x  = (float*)alloc((size_t)NTOK * DMODEL * 4);
  u16* h    = (u16*)alloc((size_t)NTOK * DMODEL * 2);
  u16* qkv  = (u16*)alloc((size_t)NTOK * 3 * DMODEL * 2);
  u16* vtb  = (u16*)alloc((size_t)NTOK * DMODEL * 2);
  u16* yb   = (u16*)alloc((size_t)NTOK * DMODEL * 2);
  u16* ffb  = (u16*)alloc((size_t)NTOK * DFF * 2);
  u16* opart = (u16*)alloc((size_t)NSPLIT * NB * NHEAD * SEQ * DHEAD * 2);
  float* lpart = (float*)alloc((size_t)NSPLIT * NB * NHEAD * SEQ * 4);

  const size_t dd = (size_t)DMODEL * DMODEL, dff = (size_t)DMODEL * DFF;
  const size_t perLayerElems = 4 * dd + 2 * dff;
  const size_t lmhT_bytes = (size_t)NVOCAB * DMODEL * 2;

  // Weight-transpose tiers (ws-gated): all-layers batched > per-layer.
  const size_t wAll_bytes = (size_t)NLAYER * perLayerElems * 2;
  const size_t wT_bytes = perLayerElems * 2;
  int tier;
  u16 *wAll = nullptr, *wT = nullptr, *lmhT = nullptr;
  if (off + wAll_bytes + lmhT_bytes <= ws_size) {
    tier = 2; wAll = (u16*)alloc(wAll_bytes); lmhT = (u16*)alloc(lmhT_bytes);
  } else if (off + wT_bytes + lmhT_bytes <= ws_size) {
    tier = 1; wT = (u16*)alloc(wT_bytes); lmhT = (u16*)alloc(lmhT_bytes);
  } else {
    tier = 0; wT = (u16*)alloc(wT_bytes);
  }

  embed_kernel<<<NTOK, 256, 0, stream>>>(idx, tok, x);

  if (tier == 2)
    transpose6_kernel<<<dim3(3072, NLAYER), 256, 0, stream>>>(
        wq, wk, wv, wo, w1, w2, wAll, perLayerElems);

  const int gQKV = (NTOK / 64) * (3 * DMODEL / 128);
  const int gFF1 = (NTOK / 64) * (DFF / 128);
  const int gD64 = (DMODEL / 64) * (NTOK / 64);
  const int gATT = NSPLIT * NB * NHEAD * (SEQ / 32);

  for (int layer = 0; layer < NLAYER; layer++) {
    u16 *base;
    if (tier == 2) {
      base = wAll + (size_t)layer * perLayerElems;
    } else {
      base = wT;
      transpose6_kernel<<<dim3(3072, 1), 256, 0, stream>>>(
          wq + layer * dd, wk + layer * dd, wv + layer * dd, wo + layer * dd,
          w1 + layer * dff, w2 + layer * dff, wT, 0);
    }
    u16* wqT = base;
    u16* woT = base + 3 * dd;
    u16* w1T = base + 4 * dd;
    u16* w2T = w1T + dff;

    ln_kernel<<<NTOK, 256, 0, stream>>>(x, ln1w + layer * DMODEL, ln1b + layer * DMODEL, h);
    gemm_bt<EPI_QKV, 64, 128><<<gQKV, 256, 0, stream>>>(h, wqT, nullptr, qkv, nullptr,
                                                        NTOK, 3 * DMODEL, DMODEL, 3 * DMODEL);
    vtrans_kernel<<<dim3(SEQ / 32, DHEAD / 32, NB * NHEAD), 256, 0, stream>>>(qkv, vtb);
    attn_partial<<<gATT, 64, 0, stream>>>(qkv, vtb, opart, lpart);
    attn_combine<<<NB * SEQ, 256, 0, stream>>>(opart, lpart, yb);
    gemm_bt<EPI_RESID, 64, 64><<<gD64, 256, 0, stream>>>(yb, woT, nullptr, nullptr, x,
                                                         NTOK, DMODEL, DMODEL, DMODEL);
    ln_kernel<<<NTOK, 256, 0, stream>>>(x, ln2w + layer * DMODEL, ln2b + layer * DMODEL, h);
    gemm_bt<EPI_GELU_BIAS, 64, 128><<<gFF1, 256, 0, stream>>>(h, w1T, b1 + (size_t)layer * DFF, ffb,
                                                              nullptr, NTOK, DFF, DMODEL, DFF);
    gemm_bt<EPI_RESID_BIAS, 64, 64><<<gD64, 256, 0, stream>>>(ffb, w2T, b2 + (size_t)layer * DMODEL,
                                                              nullptr, x, NTOK, DMODEL, DFF, DMODEL);
  }

  ln_kernel<<<NTOK, 256, 0, stream>>>(x, lnfw, lnfb, h);

  if (tier >= 1) {
    transpose64_b<<<dim3(NVOCAB / 64, DMODEL / 64), 256, 0, stream>>>(lmh, lmhT, DMODEL, NVOCAB);
    const int gLM = (NVOCAB / 128) * (NTOK / 128);
    gemm_bt<EPI_LOGITS, 128, 128><<<gLM, 256, 0, stream>>>(
        h, lmhT, nullptr, nullptr, out, NTOK, NVOCAB, DMODEL, NVOCAB);
  } else {
    for (int c = 0; c < NVOCAB / VCHUNK; c++) {
      transpose64_b<<<dim3(VCHUNK / 64, DMODEL / 64), 256, 0, stream>>>(
          lmh + (size_t)c * VCHUNK, wT, DMODEL, NVOCAB);
      gemm_bt<EPI_LOGITS, 128, 128><<<(VCHUNK / 128) * (NTOK / 128), 256, 0, stream>>>(
          h, wT, nullptr, nullptr, out + (size_t)c * VCHUNK,
          NTOK, VCHUNK, DMODEL, NVOCAB);
    }
  }
}

// Round 20
// 1724.498 us; speedup vs baseline: 1.1702x; 1.1702x over previous
//
#include <hip/hip_runtime.h>
#include <math.h>

typedef unsigned short u16;
typedef __bf16 bfx8 __attribute__((ext_vector_type(8)));
typedef float f32x4 __attribute__((ext_vector_type(4)));

#define NLAYER  8
#define NHEAD   16
#define DMODEL  1024
#define DHEAD   64
#define DFF     4096
#define NB      2
#define SEQ     1024
#define NVOCAB  32000
#define NTOK    (NB*SEQ)
#define EPSLN   1e-5f
#define VCHUNK  6400   // lm_head fallback chunking (ws-gated)
#define NSPLIT  2      // attention split-K factor (round-6/8 verified)

__device__ __forceinline__ float bf2f(u16 u) {
  union { unsigned int i; float f; } x; x.i = ((unsigned int)u) << 16; return x.f;
}
__device__ __forceinline__ u16 f2bf(float f) {
  unsigned int x = __float_as_uint(f);
  x += 0x7fffu + ((x >> 16) & 1u);          // RNE
  return (u16)(x >> 16);
}

#if defined(__has_builtin)
#if __has_builtin(__builtin_amdgcn_global_load_lds)
#define HAVE_GLL 1
#endif
#endif

// Async global->LDS: 64 lanes x 16B. lds_base is wave-uniform; HW adds lane*16.
__device__ __forceinline__ void gll16(const void* g, void* lds_base, int lane) {
#ifdef HAVE_GLL
  __builtin_amdgcn_global_load_lds((const __attribute__((address_space(1))) unsigned int*)g,
                                   (__attribute__((address_space(3))) unsigned int*)lds_base,
                                   16, 0, 0);
  (void)lane;
#else
  *(uint4*)((char*)lds_base + lane * 16) = *(const uint4*)g;
#endif
}

enum { EPI_QKV = 0, EPI_GELU_BIAS = 1, EPI_RESID = 2, EPI_RESID_BIAS = 3, EPI_LOGITS = 4 };

// ------------------------------------------------------------------
// 2-phase dbuf GEMM, BK=32 (r13-verified structure, zero bank conflicts).
// Tile census: lm_head 128x128 (4000 blk, 5/CU) | QKV 64x128 | FF1 64x128 |
// wo,FF2 64x64 (2/CU). Block-level TLP is the only lever that ever paid
// (r3/r12/r17); pipelining closed (r8/r10/r14). Weight transposes MUST stay
// per-layer, immediately before use: r19 showed up-front batching makes
// B-loads L3-cold (+286us). Swizzle key (row>>1)&3, both-sides involution.
// ------------------------------------------------------------------
template <int EPI, int BM, int BN>
__global__ __launch_bounds__(256) void gemm_bt(
    const u16* __restrict__ A, const u16* __restrict__ Bt,
    const float* __restrict__ bias, u16* __restrict__ outb,
    float* __restrict__ outf, int M, int N, int K, int ldc)
{
  constexpr int ARND = BM / 64;
  constexpr int BRND = BN / 64;
  constexpr int MF = BM / 32;
  constexpr int NF = BN / 32;
  constexpr int ABYTES = BM * 32 * 2;
  constexpr int BBYTES = BN * 32 * 2;
  __shared__ __align__(16) u16 sA[2][BM * 32];
  __shared__ __align__(16) u16 sB[2][BN * 32];

  const int tid  = threadIdx.x;
  const int w    = tid >> 6;
  const int lane = tid & 63;
  const int l16  = lane & 15;
  const int hi   = lane >> 4;
  const int wm   = w >> 1;
  const int wn   = w & 1;

  const int nwg = gridDim.x;
  const int MB  = M / BM;
  const int orig = blockIdx.x;
  const int xcd = orig & 7, li = orig >> 3;
  const int q = nwg >> 3, r = nwg & 7;
  const int work = (xcd < r ? xcd * (q + 1) : r * (q + 1) + (xcd - r) * q) + li;
  const int m0 = (work % MB) * BM;
  const int n0 = (work / MB) * BN;

  const int srow = lane >> 2;
  const int su   = lane & 3;

  const u16* gA[ARND]; const u16* gB[BRND];
  int laOff[ARND]; int lbOff[BRND];
#pragma unroll
  for (int r2 = 0; r2 < ARND; r2++) {
    const int row = r2 * 64 + w * 16 + srow;
    const int gu = su ^ ((row >> 1) & 3);
    gA[r2] = A + (size_t)(m0 + row) * K + gu * 8;
    laOff[r2] = (r2 * 64 + w * 16) * 64;
  }
#pragma unroll
  for (int r2 = 0; r2 < BRND; r2++) {
    const int row = r2 * 64 + w * 16 + srow;
    const int gu = su ^ ((row >> 1) & 3);
    gB[r2] = Bt + (size_t)(n0 + row) * K + gu * 8;
    lbOff[r2] = (r2 * 64 + w * 16) * 64;
  }

  f32x4 acc[MF][NF];
#pragma unroll
  for (int i = 0; i < MF; i++)
#pragma unroll
    for (int j = 0; j < NF; j++)
#pragma unroll
      for (int r2 = 0; r2 < 4; r2++) acc[i][j][r2] = 0.0f;

#pragma unroll
  for (int r2 = 0; r2 < ARND; r2++) { gll16(gA[r2], (char*)sA[0] + laOff[r2], lane); gA[r2] += 32; }
#pragma unroll
  for (int r2 = 0; r2 < BRND; r2++) { gll16(gB[r2], (char*)sB[0] + lbOff[r2], lane); gB[r2] += 32; }
  __syncthreads();

  const int NT = K >> 5;
  int cur = 0;
  for (int t = 0; t < NT; ++t) {
    if (t + 1 < NT) {
      char* nA = (char*)sA[0] + (cur ^ 1) * ABYTES;
      char* nB = (char*)sB[0] + (cur ^ 1) * BBYTES;
#pragma unroll
      for (int r2 = 0; r2 < ARND; r2++) { gll16(gA[r2], nA + laOff[r2], lane); gA[r2] += 32; }
#pragma unroll
      for (int r2 = 0; r2 < BRND; r2++) { gll16(gB[r2], nB + lbOff[r2], lane); gB[r2] += 32; }
    }

    const char* cA = (const char*)sA[0] + cur * ABYTES;
    const char* cB = (const char*)sB[0] + cur * BBYTES;
    bfx8 aF[MF], bF[NF];
#pragma unroll
    for (int i = 0; i < MF; i++) {
      const int row = wm * (BM / 2) + i * 16 + l16;
      aF[i] = *(const bfx8*)(cA + row * 64 + ((hi ^ ((row >> 1) & 3)) << 4));
    }
#pragma unroll
    for (int j = 0; j < NF; j++) {
      const int row = wn * (BN / 2) + j * 16 + l16;
      bF[j] = *(const bfx8*)(cB + row * 64 + ((hi ^ ((row >> 1) & 3)) << 4));
    }
#pragma unroll
    for (int i = 0; i < MF; i++)
#pragma unroll
      for (int j = 0; j < NF; j++)
        acc[i][j] = __builtin_amdgcn_mfma_f32_16x16x32_bf16(aF[i], bF[j], acc[i][j], 0, 0, 0);
    __syncthreads();
    cur ^= 1;
  }

  const int rbase = m0 + wm * (BM / 2);
  const int cbase = n0 + wn * (BN / 2);
#pragma unroll
  for (int i = 0; i < MF; i++) {
#pragma unroll
    for (int j = 0; j < NF; j++) {
      const int gcol = cbase + j * 16 + l16;
      float bv = 0.0f;
      if constexpr (EPI == EPI_GELU_BIAS || EPI == EPI_RESID_BIAS) bv = bias[gcol];
#pragma unroll
      for (int r2 = 0; r2 < 4; r2++) {
        const int grow = rbase + i * 16 + hi * 4 + r2;
        float v = acc[i][j][r2];
        const size_t oi = (size_t)grow * ldc + gcol;
        if constexpr (EPI == EPI_QKV) {
          outb[oi] = f2bf(v);
        } else if constexpr (EPI == EPI_GELU_BIAS) {
          v += bv;
          v = 0.5f * v * (1.0f + erff(v * 0.70710678118654752f));
          outb[oi] = f2bf(v);
        } else if constexpr (EPI == EPI_RESID) {
          outf[oi] += v;
        } else if constexpr (EPI == EPI_RESID_BIAS) {
          outf[oi] += v + bv;
        } else {
          outf[oi] = v;
        }
      }
    }
  }
}

// LayerNorm, single-pass (sum + sumsq through one shuffle tree).
__global__ __launch_bounds__(256) void ln_kernel(
    const float* __restrict__ x, const float* __restrict__ w,
    const float* __restrict__ b, u16* __restrict__ out)
{
  const int row = blockIdx.x;
  const int tid = threadIdx.x;
  const float* xr = x + (size_t)row * DMODEL;
  float4 v = *(const float4*)(xr + tid * 4);
  __shared__ float sbuf[4], qbuf[4];
  float s = v.x + v.y + v.z + v.w;
  float ss = v.x * v.x + v.y * v.y + v.z * v.z + v.w * v.w;
#pragma unroll
  for (int o = 32; o > 0; o >>= 1) { s += __shfl_xor(s, o, 64); ss += __shfl_xor(ss, o, 64); }
  if ((tid & 63) == 0) { sbuf[tid >> 6] = s; qbuf[tid >> 6] = ss; }
  __syncthreads();
  const float mean = (sbuf[0] + sbuf[1] + sbuf[2] + sbuf[3]) * (1.0f / DMODEL);
  const float ex2  = (qbuf[0] + qbuf[1] + qbuf[2] + qbuf[3]) * (1.0f / DMODEL);
  const float rstd = rsqrtf(ex2 - mean * mean + EPSLN);
  const int c = tid * 4;
  float dv[4] = {v.x - mean, v.y - mean, v.z - mean, v.w - mean};
#pragma unroll
  for (int e = 0; e < 4; e++)
    out[(size_t)row * DMODEL + c + e] = f2bf(dv[e] * rstd * w[c + e] + b[c + e]);
}

// x = tok_emb[idx] + sinusoidal PE, fp32 in -> fp32 out.
__global__ __launch_bounds__(256) void embed_kernel(
    const int* __restrict__ idx, const float* __restrict__ tok, float* __restrict__ x)
{
  const int row = blockIdx.x;
  const int l = row & (SEQ - 1);
  const int t = idx[row];
  const int d = threadIdx.x * 4;
#pragma unroll
  for (int e = 0; e < 4; e++) {
    const int dd = d + e;
    const float freq = expf((float)(dd & ~1) * (-9.210340371976184f / (float)DMODEL));
    const float ang = (float)l * freq;
    const float pe = (dd & 1) ? cosf(ang) : sinf(ang);
    x[(size_t)row * DMODEL + dd] = tok[(size_t)t * DMODEL + dd] + pe;
  }
}

// 64x64-tile transpose body: fp32 in -> bf16 out, float4 loads, packed
// ushort2 stores. tile[64][65] breaks bank conflicts.
__device__ __forceinline__ void transpose64_body(
    const float* __restrict__ in, u16* __restrict__ out,
    int rows, int cols, int c0, int r0)
{
  __shared__ float tile[64][65];
  const int lx = threadIdx.x & 15, ly = threadIdx.x >> 4;
#pragma unroll
  for (int ii = 0; ii < 4; ii++) {
    const int rr = ly + ii * 16;
    const float4 v = *(const float4*)&in[(size_t)(r0 + rr) * cols + c0 + lx * 4];
    tile[rr][lx * 4 + 0] = v.x;
    tile[rr][lx * 4 + 1] = v.y;
    tile[rr][lx * 4 + 2] = v.z;
    tile[rr][lx * 4 + 3] = v.w;
  }
  __syncthreads();
  const int sx = threadIdx.x & 31, sy = threadIdx.x >> 5;
#pragma unroll
  for (int ii = 0; ii < 8; ii++) {
    const int cc = sy + ii * 8;
    const unsigned int a = f2bf(tile[sx * 2][cc]);
    const unsigned int b = f2bf(tile[sx * 2 + 1][cc]);
    *(unsigned int*)&out[(size_t)(c0 + cc) * rows + r0 + sx * 2] = a | (b << 16);
  }
}

// Generic 64x64 transpose: out[c][r] = (bf16)in[r][c].
__global__ __launch_bounds__(256) void transpose64_b(
    const float* __restrict__ in, u16* __restrict__ out, int rows, int cols)
{
  transpose64_body(in, out, rows, cols, blockIdx.x * 64, blockIdx.y * 64);
}

// Fused per-layer weight transpose, 64x64 tiles: 3072 blocks.
// MUST run per layer, immediately before that layer's GEMMs (r19 lesson:
// up-front batching makes weight reads L3-cold, +286us).
__global__ __launch_bounds__(256) void transpose6_kernel(
    const float* __restrict__ wq, const float* __restrict__ wk,
    const float* __restrict__ wv, const float* __restrict__ wo,
    const float* __restrict__ w1, const float* __restrict__ w2,
    u16* __restrict__ wT)
{
  const size_t dd = (size_t)DMODEL * DMODEL, dff = (size_t)DMODEL * DFF;
  const int t = blockIdx.x;
  const float* in; u16* out; int rows, cols, cx, cy;
  if (t < 1024) {
    const int mat = t >> 8, tl = t & 255;
    in = (mat == 0) ? wq : (mat == 1) ? wk : (mat == 2) ? wv : wo;
    out = wT + (size_t)mat * dd; rows = DMODEL; cols = DMODEL;
    cx = tl & 15; cy = tl >> 4;
  } else if (t < 2048) {
    const int tl = t - 1024;
    in = w1; out = wT + 4 * dd; rows = DMODEL; cols = DFF;
    cx = tl & 63; cy = tl >> 6;
  } else {
    const int tl = t - 2048;
    in = w2; out = wT + 4 * dd + dff; rows = DFF; cols = DMODEL;
    cx = tl & 15; cy = tl >> 4;
  }
  transpose64_body(in, out, rows, cols, cx * 64, cy * 64);
}

// vt[(b*NH+h)*DHEAD + d][l] = qkv[b*SEQ+l][2*DMODEL + h*DHEAD + d]  (bf16)
__global__ __launch_bounds__(256) void vtrans_kernel(
    const u16* __restrict__ qkv, u16* __restrict__ vt)
{
  __shared__ u16 tile[32][33];
  const int bh = blockIdx.z;
  const int b = bh >> 4, hh = bh & 15;
  const int l0 = blockIdx.x * 32, d0 = blockIdx.y * 32;
  const int tx = threadIdx.x & 31, ty = threadIdx.x >> 5;
#pragma unroll
  for (int i = ty; i < 32; i += 8)
    tile[i][tx] = qkv[(size_t)(b * SEQ + l0 + i) * (3 * DMODEL) + 2 * DMODEL + hh * DHEAD + d0 + tx];
  __syncthreads();
#pragma unroll
  for (int i = ty; i < 32; i += 8)
    vt[(size_t)(bh * DHEAD + d0 + i) * SEQ + l0 + tx] = tile[tx][i];
}

// P-tile LDS: 32 rows x 128 cols bf16 (256B rows = 16x16B units).
__device__ __forceinline__ int plds_byte(int row, int col) {
  const int cu = col >> 3;
  const int scu = (cu & 8) | ((cu & 7) ^ (row & 7));
  return row * 256 + scu * 16 + (col & 7) * 2;
}

// Split-K flash attention partial, no max-tracking (r9 math), KVBLK=128,
// 1D grid + XCD chunk map. opart stored bf16 (r19-verified: absmax unchanged).
__global__ __launch_bounds__(64) void attn_partial(
    const u16* __restrict__ qkv, const u16* __restrict__ vt,
    u16* __restrict__ opart, float* __restrict__ lpart)
{
  __shared__ __align__(16) u16 p_lds[32 * 128];
  const int lane = threadIdx.x;
  const int l16 = lane & 15, hi = lane >> 4;

  const int orig = blockIdx.x;
  const int work = (orig & 7) * (NSPLIT * NB * NHEAD * (SEQ / 32) / 8) + (orig >> 3);
  const int qt = work & 31;
  const int t1 = work >> 5;
  const int hh = t1 & 15;
  const int t2 = t1 >> 4;
  const int b  = t2 & 1;
  const int sp = t2 >> 1;

  const int q0 = qt * 32;
  const int T = (q0 + 159) >> 7;
  const int t_lo = (T * sp) >> 1;
  const int t_hi = (T * (sp + 1)) >> 1;

  const u16* qptr = qkv;
  const u16* kptr = qkv + DMODEL;
  const size_t rs3 = 3 * DMODEL;
  const size_t hoff = (size_t)hh * DHEAD;

  bfx8 aQ[2][2];
#pragma unroll
  for (int mt = 0; mt < 2; mt++)
#pragma unroll
    for (int kf = 0; kf < 2; kf++)
      aQ[mt][kf] = *(const bfx8*)&qptr[(size_t)(b * SEQ + q0 + mt * 16 + l16) * rs3 + hoff + kf * 32 + hi * 8];

  f32x4 o[2][4];
  float ssum[2][4];
#pragma unroll
  for (int mt = 0; mt < 2; mt++)
#pragma unroll
    for (int r = 0; r < 4; r++) ssum[mt][r] = 0.0f;
#pragma unroll
  for (int mt = 0; mt < 2; mt++)
#pragma unroll
    for (int dt = 0; dt < 4; dt++)
#pragma unroll
      for (int r = 0; r < 4; r++) o[mt][dt][r] = 0.0f;

  for (int kt = t_lo; kt < t_hi; kt++) {
    const int k0 = kt * 128;
    const bool diag = (kt == T - 1);

    float rs[2][4];
#pragma unroll
    for (int mt = 0; mt < 2; mt++)
#pragma unroll
      for (int r = 0; r < 4; r++) rs[mt][r] = 0.0f;

#pragma unroll
    for (int hf = 0; hf < 2; hf++) {
      const int kh0 = k0 + hf * 64;
      bfx8 bK[4][2];
#pragma unroll
      for (int nt = 0; nt < 4; nt++)
#pragma unroll
        for (int kf = 0; kf < 2; kf++)
          bK[nt][kf] = *(const bfx8*)&kptr[(size_t)(b * SEQ + kh0 + nt * 16 + l16) * rs3 + hoff + kf * 32 + hi * 8];

      f32x4 s[2][4];
#pragma unroll
      for (int mt = 0; mt < 2; mt++)
#pragma unroll
        for (int nt = 0; nt < 4; nt++) {
#pragma unroll
          for (int r = 0; r < 4; r++) s[mt][nt][r] = 0.0f;
          s[mt][nt] = __builtin_amdgcn_mfma_f32_16x16x32_bf16(aQ[mt][0], bK[nt][0], s[mt][nt], 0, 0, 0);
          s[mt][nt] = __builtin_amdgcn_mfma_f32_16x16x32_bf16(aQ[mt][1], bK[nt][1], s[mt][nt], 0, 0, 0);
        }

#pragma unroll
      for (int mt = 0; mt < 2; mt++) {
#pragma unroll
        for (int r = 0; r < 4; r++) {
          const int row_l = mt * 16 + hi * 4 + r;
          const int qrow = q0 + row_l;
#pragma unroll
          for (int nt = 0; nt < 4; nt++) {
            const float sv = s[mt][nt][r] * 0.125f;
            const bool mask = diag && (kh0 + nt * 16 + l16 > qrow);
            const float p = mask ? 0.0f : __expf(sv);
            rs[mt][r] += p;
            *(__bf16*)((char*)p_lds + plds_byte(row_l, hf * 64 + nt * 16 + l16)) = (__bf16)p;
          }
        }
      }
    }

#pragma unroll
    for (int mt = 0; mt < 2; mt++)
#pragma unroll
      for (int r = 0; r < 4; r++) {
        float rsum = rs[mt][r];
#pragma unroll
        for (int t = 1; t < 16; t <<= 1) rsum += __shfl_xor(rsum, t, 64);
        ssum[mt][r] += rsum;
      }
    __syncthreads();

    const size_t vbase = (size_t)(b * NHEAD + hh) * DHEAD * SEQ;
#pragma unroll
    for (int hf = 0; hf < 2; hf++) {
      bfx8 pa[2][2];
#pragma unroll
      for (int mt = 0; mt < 2; mt++) {
        const int row = mt * 16 + l16;
#pragma unroll
        for (int kf = 0; kf < 2; kf++) {
          const int u = hf * 8 + kf * 4 + hi;
          const int su_ = (u & 8) | ((u & 7) ^ (row & 7));
          pa[mt][kf] = *(const bfx8*)((const char*)p_lds + row * 256 + su_ * 16);
        }
      }
      bfx8 bV[4][2];
#pragma unroll
      for (int dt = 0; dt < 4; dt++)
#pragma unroll
        for (int kf = 0; kf < 2; kf++)
          bV[dt][kf] = *(const bfx8*)&vt[vbase + (size_t)(dt * 16 + l16) * SEQ + k0 + hf * 64 + kf * 32 + hi * 8];
#pragma unroll
      for (int mt = 0; mt < 2; mt++)
#pragma unroll
        for (int dt = 0; dt < 4; dt++) {
          o[mt][dt] = __builtin_amdgcn_mfma_f32_16x16x32_bf16(pa[mt][0], bV[dt][0], o[mt][dt], 0, 0, 0);
          o[mt][dt] = __builtin_amdgcn_mfma_f32_16x16x32_bf16(pa[mt][1], bV[dt][1], o[mt][dt], 0, 0, 0);
        }
    }
    __syncthreads();
  }

  const size_t pbase = (((size_t)sp * NB + b) * NHEAD + hh) * SEQ + q0;
#pragma unroll
  for (int mt = 0; mt < 2; mt++) {
#pragma unroll
    for (int r = 0; r < 4; r++) {
      const int row_l = mt * 16 + hi * 4 + r;
      const size_t rg = pbase + row_l;
      if (l16 == 0) lpart[rg] = ssum[mt][r];
#pragma unroll
      for (int dt = 0; dt < 4; dt++)
        opart[rg * DHEAD + dt * 16 + l16] = f2bf(o[mt][dt][r]);
    }
  }
}

// Combine NSPLIT partials (all weights 1, no max) -> y bf16.
__global__ __launch_bounds__(256) void attn_combine(
    const u16* __restrict__ opart, const float* __restrict__ lpart,
    u16* __restrict__ y)
{
  const int row = blockIdx.x;
  const int b = row >> 10;
  const int l = row & (SEQ - 1);
  const int t = threadIdx.x;
  const int hh = t >> 4;
  const int d0 = (t & 15) * 4;
  const size_t base = ((size_t)b * NHEAD + hh) * SEQ + l;
  const size_t stride = (size_t)NB * NHEAD * SEQ;
  float wsum = 0.0f;
  float4 acc = make_float4(0.f, 0.f, 0.f, 0.f);
#pragma unroll
  for (int i = 0; i < NSPLIT; i++) {
    wsum += lpart[base + i * stride];
    const ushort4 ov = *(const ushort4*)&opart[(base + i * stride) * DHEAD + d0];
    acc.x += bf2f(ov.x); acc.y += bf2f(ov.y);
    acc.z += bf2f(ov.z); acc.w += bf2f(ov.w);
  }
  const float dn = 1.0f / wsum;
  u16* yp = y + (size_t)row * DMODEL + hh * DHEAD + d0;
  yp[0] = f2bf(acc.x * dn);
  yp[1] = f2bf(acc.y * dn);
  yp[2] = f2bf(acc.z * dn);
  yp[3] = f2bf(acc.w * dn);
}

extern "C" void kernel_launch(void* const* d_in, const int* in_sizes, int n_in,
                              void* d_out, int out_size, void* d_ws, size_t ws_size,
                              hipStream_t stream)
{
  (void)in_sizes; (void)n_in; (void)out_size;
  const int*   idx  = (const int*)d_in[0];
  const float* tok  = (const float*)d_in[1];
  const float* ln1w = (const float*)d_in[2];
  const float* ln1b = (const float*)d_in[3];
  const float* wq   = (const float*)d_in[4];
  const float* wk   = (const float*)d_in[5];
  const float* wv   = (const float*)d_in[6];
  const float* wo   = (const float*)d_in[7];
  const float* ln2w = (const float*)d_in[8];
  const float* ln2b = (const float*)d_in[9];
  const float* w1   = (const float*)d_in[10];
  const float* b1   = (const float*)d_in[11];
  const float* w2   = (const float*)d_in[12];
  const float* b2   = (const float*)d_in[13];
  const float* lnfw = (const float*)d_in[14];
  const float* lnfb = (const float*)d_in[15];
  const float* lmh  = (const float*)d_in[16];
  float* out = (float*)d_out;

  char* ws = (char*)d_ws;
  size_t off = 0;
  auto alloc = [&](size_t bytes) -> void* {
    void* p = ws + off;
    off += (bytes + 255) & ~(size_t)255;
    return p;
  };
  float* x  = (float*)alloc((size_t)NTOK * DMODEL * 4);
  u16* h    = (u16*)alloc((size_t)NTOK * DMODEL * 2);
  u16* qkv  = (u16*)alloc((size_t)NTOK * 3 * DMODEL * 2);
  u16* vtb  = (u16*)alloc((size_t)NTOK * DMODEL * 2);
  u16* yb   = (u16*)alloc((size_t)NTOK * DMODEL * 2);
  u16* ffb  = (u16*)alloc((size_t)NTOK * DFF * 2);
  u16* opart = (u16*)alloc((size_t)NSPLIT * NB * NHEAD * SEQ * DHEAD * 2);
  float* lpart = (float*)alloc((size_t)NSPLIT * NB * NHEAD * SEQ * 4);

  const size_t dd = (size_t)DMODEL * DMODEL, dff = (size_t)DMODEL * DFF;
  const size_t perLayerElems = 4 * dd + 2 * dff;
  const size_t wT_bytes = perLayerElems * 2;
  const size_t lmhT_bytes = (size_t)NVOCAB * DMODEL * 2;

  u16* wT = (u16*)alloc(wT_bytes);
  const bool full_lmh = (off + lmhT_bytes) <= ws_size;
  u16* lmhT = full_lmh ? (u16*)alloc(lmhT_bytes) : nullptr;

  embed_kernel<<<NTOK, 256, 0, stream>>>(idx, tok, x);

  const int gQKV = (NTOK / 64) * (3 * DMODEL / 128);
  const int gFF1 = (NTOK / 64) * (DFF / 128);
  const int gD64 = (DMODEL / 64) * (NTOK / 64);
  const int gATT = NSPLIT * NB * NHEAD * (SEQ / 32);

  u16* wqT = wT;
  u16* woT = wT + 3 * dd;
  u16* w1T = wT + 4 * dd;
  u16* w2T = w1T + dff;

  for (int layer = 0; layer < NLAYER; layer++) {
    transpose6_kernel<<<3072, 256, 0, stream>>>(
        wq + layer * dd, wk + layer * dd, wv + layer * dd, wo + layer * dd,
        w1 + layer * dff, w2 + layer * dff, wT);

    ln_kernel<<<NTOK, 256, 0, stream>>>(x, ln1w + layer * DMODEL, ln1b + layer * DMODEL, h);
    gemm_bt<EPI_QKV, 64, 128><<<gQKV, 256, 0, stream>>>(h, wqT, nullptr, qkv, nullptr,
                                                        NTOK, 3 * DMODEL, DMODEL, 3 * DMODEL);
    vtrans_kernel<<<dim3(SEQ / 32, DHEAD / 32, NB * NHEAD), 256, 0, stream>>>(qkv, vtb);
    attn_partial<<<gATT, 64, 0, stream>>>(qkv, vtb, opart, lpart);
    attn_combine<<<NB * SEQ, 256, 0, stream>>>(opart, lpart, yb);
    gemm_bt<EPI_RESID, 64, 64><<<gD64, 256, 0, stream>>>(yb, woT, nullptr, nullptr, x,
                                                         NTOK, DMODEL, DMODEL, DMODEL);
    ln_kernel<<<NTOK, 256, 0, stream>>>(x, ln2w + layer * DMODEL, ln2b + layer * DMODEL, h);
    gemm_bt<EPI_GELU_BIAS, 64, 128><<<gFF1, 256, 0, stream>>>(h, w1T, b1 + (size_t)layer * DFF, ffb,
                                                              nullptr, NTOK, DFF, DMODEL, DFF);
    gemm_bt<EPI_RESID_BIAS, 64, 64><<<gD64, 256, 0, stream>>>(ffb, w2T, b2 + (size_t)layer * DMODEL,
                                                              nullptr, x, NTOK, DMODEL, DFF, DMODEL);
  }

  ln_kernel<<<NTOK, 256, 0, stream>>>(x, lnfw, lnfb, h);

  if (full_lmh) {
    transpose64_b<<<dim3(NVOCAB / 64, DMODEL / 64), 256, 0, stream>>>(lmh, lmhT, DMODEL, NVOCAB);
    const int gLM = (NVOCAB / 128) * (NTOK / 128);
    gemm_bt<EPI_LOGITS, 128, 128><<<gLM, 256, 0, stream>>>(
        h, lmhT, nullptr, nullptr, out, NTOK, NVOCAB, DMODEL, NVOCAB);
  } else {
    for (int c = 0; c < NVOCAB / VCHUNK; c++) {
      transpose64_b<<<dim3(VCHUNK / 64, DMODEL / 64), 256, 0, stream>>>(
          lmh + (size_t)c * VCHUNK, wT, DMODEL, NVOCAB);
      gemm_bt<EPI_LOGITS, 128, 128><<<(VCHUNK / 128) * (NTOK / 128), 256, 0, stream>>>(
          h, wT, nullptr, nullptr, out + (size_t)c * VCHUNK,
          NTOK, VCHUNK, DMODEL, NVOCAB);
    }
  }
}